// Round 6
// baseline (28.581 us; speedup 1.0000x reference)
//
#include <hip/hip_runtime.h>

static constexpr int H = 2048;
static constexpr int W = 2048;
static constexpr int BLOCK = 256;
static constexpr int PXT = 2;                             // pixels per thread
static constexpr int NBLOCKS = H * (W / (BLOCK * PXT));   // 8192
static constexpr int RBLOCK = 1024;

__device__ __forceinline__ float fexp2(float x){ return __builtin_amdgcn_exp2f(x); }
__device__ __forceinline__ float flog2(float x){ return __builtin_amdgcn_logf(x); }
__device__ __forceinline__ float frcp (float x){ return __builtin_amdgcn_rcpf(x); }

static constexpr float S_   = 0.84932180028801905f;   // sqrt(0.5*log2(e))
static constexpr float LN2_ = 0.69314718055994531f;

// One pixel's contribution, all named scalars.
//   t=(d*S)^2, e=exp2(-t)=exp(-d^2/2); Sp=sum e*t; G=sum e
//   pacc = Sp*ip + Sq*iq + log2(Gp*Gq) + 2*sum m*log2 m ; out = -ln2*sum(pacc)
__device__ __forceinline__ float pixel_term(
    float aul, float auc, float aur, float adl, float adc, float adr, float ca,
    float heAl, float heAr, float htAl, float htAr,
    float bul, float buc, float bur, float bdl, float bdc, float bdr, float cb,
    float heBl, float heBr, float htBl, float htBr)
{
    float Gp = 1.f + heAl + heAr;
    float Sp = htAl + htAr;
    float Gq = 1.f + heBl + heBr;
    float Sq = htBl + htBr;

    float d, t, e;
#define NB(nv, cv, G, Ssum, ev)                                   \
    d = (nv) - (cv); d *= S_; t = d * d; e = fexp2(-t);           \
    G += e; Ssum = fmaf(e, t, Ssum); const float ev = e;

    NB(aul, ca, Gp, Sp, veA0)  NB(auc, ca, Gp, Sp, veA1)  NB(aur, ca, Gp, Sp, veA2)
    NB(adl, ca, Gp, Sp, veA3)  NB(adc, ca, Gp, Sp, veA4)  NB(adr, ca, Gp, Sp, veA5)
    NB(bul, cb, Gq, Sq, veB0)  NB(buc, cb, Gq, Sq, veB1)  NB(bur, cb, Gq, Sq, veB2)
    NB(bdl, cb, Gq, Sq, veB3)  NB(bdc, cb, Gq, Sq, veB4)  NB(bdr, cb, Gq, Sq, veB5)
#undef NB

    const float ip = frcp(Gp), iq = frcp(Gq);
    const float hp = 0.5f * ip, hq = 0.5f * iq;

    float m = hp + hq;                       // center tap (g=1 for both)
    float mll = m * flog2(m);
#define MT(ea, eb)                                                \
    m = fmaf((ea), hp, (eb) * hq); mll = fmaf(m, flog2(m), mll);
    MT(heAl, heBl)  MT(heAr, heBr)
    MT(veA0, veB0)  MT(veA1, veB1)  MT(veA2, veB2)
    MT(veA3, veB3)  MT(veA4, veB4)  MT(veA5, veB5)
#undef MT

    return fmaf(Sp, ip, Sq * iq) + flog2(Gp * Gq) + 2.f * mll;
}

// __launch_bounds__(256, 6): 84-VGPR cap -> 6 waves/SIMD. Round-5 post-mortem:
// (256,4) left only 4 waves/SIMD; testing the occupancy-stall hypothesis.
__global__ __launch_bounds__(BLOCK, 6) void jsd_pixel_kernel(
    const float* __restrict__ A, const float* __restrict__ B,
    float* __restrict__ partial)
{
    const int bid  = blockIdx.x;
    const int y    = bid >> 2;                       // 4 blocks per row
    const int x0   = ((bid & 3) << 9) + (threadIdx.x << 1);
    const int base = y * W + x0;
    const bool hasL = (x0 > 0);
    const bool hasR = (x0 + PXT < W);

    // Named row scalars: col indices x0-1, x0, x0+1, x0+2.
#define LOAD_ROW(p0,p1,p2,p3, ptr, off)                           \
    { const float2 q_ = *(const float2*)((ptr) + (off));          \
      p1 = q_.x; p2 = q_.y;                                       \
      p0 = hasL ? (ptr)[(off) - 1]   : 0.f;                       \
      p3 = hasR ? (ptr)[(off) + PXT] : 0.f; }

    float a10,a11,a12,a13, b10,b11,b12,b13;
    float a00,a01,a02,a03, b00,b01,b02,b03;
    float a20,a21,a22,a23, b20,b21,b22,b23;

    LOAD_ROW(a10,a11,a12,a13, A, base)
    LOAD_ROW(b10,b11,b12,b13, B, base)
    if (y > 0) {                                      // block-uniform branch
        LOAD_ROW(a00,a01,a02,a03, A, base - W)
        LOAD_ROW(b00,b01,b02,b03, B, base - W)
    } else {
        a00=a01=a02=a03=0.f; b00=b01=b02=b03=0.f;
    }
    if (y < H - 1) {
        LOAD_ROW(a20,a21,a22,a23, A, base + W)
        LOAD_ROW(b20,b21,b22,b23, B, base + W)
    } else {
        a20=a21=a22=a23=0.f; b20=b21=b22=b23=0.f;
    }
#undef LOAD_ROW

    // Horizontal pair exps (middle row), shared between adjacent pixels.
#define HP(he, ht, l, r)                                          \
    float he, ht;                                                 \
    { float d_ = (r) - (l); d_ *= S_; const float t_ = d_ * d_;   \
      he = fexp2(-t_); ht = he * t_; }
    HP(heA0, htA0, a10, a11)  HP(heA1, htA1, a11, a12)  HP(heA2, htA2, a12, a13)
    HP(heB0, htB0, b10, b11)  HP(heB1, htB1, b11, b12)  HP(heB2, htB2, b12, b13)
#undef HP

    float pacc;
    pacc  = pixel_term(a00,a01,a02, a20,a21,a22, a11, heA0,heA1, htA0,htA1,
                       b00,b01,b02, b20,b21,b22, b11, heB0,heB1, htB0,htB1);
    pacc += pixel_term(a01,a02,a03, a21,a22,a23, a12, heA1,heA2, htA1,htA2,
                       b01,b02,b03, b21,b22,b23, b12, heB1,heB2, htB1,htB2);

    // wave64 reduce, cross-wave via LDS
    #pragma unroll
    for (int off = 32; off > 0; off >>= 1)
        pacc += __shfl_down(pacc, off, 64);

    __shared__ float wsum[BLOCK / 64];
    const int lane = threadIdx.x & 63;
    const int wid  = threadIdx.x >> 6;
    if (lane == 0) wsum[wid] = pacc;
    __syncthreads();
    if (threadIdx.x == 0)
        partial[blockIdx.x] = wsum[0] + wsum[1] + wsum[2] + wsum[3];
}

// Deterministic final reduce of NBLOCKS partials (single block, 16 waves).
__global__ __launch_bounds__(RBLOCK) void jsd_final_reduce(
    const float* __restrict__ partial, float* __restrict__ out)
{
    float s = 0.f;
    #pragma unroll
    for (int i = 0; i < NBLOCKS / RBLOCK; ++i)
        s += partial[i * RBLOCK + threadIdx.x];

    #pragma unroll
    for (int off = 32; off > 0; off >>= 1)
        s += __shfl_down(s, off, 64);

    __shared__ float wsum[RBLOCK / 64];
    const int lane = threadIdx.x & 63;
    const int wid  = threadIdx.x >> 6;
    if (lane == 0) wsum[wid] = s;
    __syncthreads();
    if (threadIdx.x == 0) {
        float t = 0.f;
        #pragma unroll
        for (int i = 0; i < RBLOCK / 64; ++i) t += wsum[i];
        out[0] = -LN2_ * t;
    }
}

extern "C" void kernel_launch(void* const* d_in, const int* in_sizes, int n_in,
                              void* d_out, int out_size, void* d_ws, size_t ws_size,
                              hipStream_t stream) {
    const float* A = (const float*)d_in[0];
    const float* B = (const float*)d_in[1];
    float* out = (float*)d_out;
    float* partial = (float*)d_ws;    // NBLOCKS floats = 32 KiB

    jsd_pixel_kernel<<<NBLOCKS, BLOCK, 0, stream>>>(A, B, partial);
    jsd_final_reduce<<<1, RBLOCK, 0, stream>>>(partial, out);
}

// Round 7
// 26.747 us; speedup vs baseline: 1.0686x; 1.0686x over previous
//
#include <hip/hip_runtime.h>

static constexpr int H = 2048;
static constexpr int W = 2048;
static constexpr int BLOCK = 256;
// 2 cols x 2 rows of pixels per thread; block tile = 512 cols x 2 rows
static constexpr int NBLOCKS = (H / 2) * (W / (BLOCK * 2));   // 1024*4 = 4096
static constexpr int RBLOCK = 1024;

__device__ __forceinline__ float fexp2(float x){ return __builtin_amdgcn_exp2f(x); }
__device__ __forceinline__ float flog2(float x){ return __builtin_amdgcn_logf(x); }
__device__ __forceinline__ float frcp (float x){ return __builtin_amdgcn_rcpf(x); }

static constexpr float S_   = 0.84932180028801905f;   // sqrt(0.5*log2(e))
static constexpr float LN2_ = 0.69314718055994531f;

// One pixel's 9-tap term. 5 precomputed (e, e*t) pairs per image (2 horizontal,
// 3 shared vertical/diagonal) + 3 inline neighbor taps (the unshared row).
//   t=(d*S)^2, e=exp2(-t)=exp(-d^2/2); G=1+sum e; S=sum e*t
//   pacc = Sp*ip + Sq*iq + log2(Gp*Gq) + 2*sum m*log2 m ; out = -ln2*sum(pacc)
__device__ __forceinline__ float pixel_term(
    float an0, float an1, float an2, float ca,
    float hAe0, float hAt0, float hAe1, float hAt1,
    float vAe0, float vAt0, float vAe1, float vAt1, float vAe2, float vAt2,
    float bn0, float bn1, float bn2, float cb,
    float hBe0, float hBt0, float hBe1, float hBt1,
    float vBe0, float vBt0, float vBe1, float vBt1, float vBe2, float vBt2)
{
    float d, t;
    d = an0 - ca; d *= S_; t = d*d; const float iAe0 = fexp2(-t); const float iAt0 = iAe0*t;
    d = an1 - ca; d *= S_; t = d*d; const float iAe1 = fexp2(-t); const float iAt1 = iAe1*t;
    d = an2 - ca; d *= S_; t = d*d; const float iAe2 = fexp2(-t); const float iAt2 = iAe2*t;
    d = bn0 - cb; d *= S_; t = d*d; const float iBe0 = fexp2(-t); const float iBt0 = iBe0*t;
    d = bn1 - cb; d *= S_; t = d*d; const float iBe1 = fexp2(-t); const float iBt1 = iBe1*t;
    d = bn2 - cb; d *= S_; t = d*d; const float iBe2 = fexp2(-t); const float iBt2 = iBe2*t;

    const float Gp = 1.f + hAe0 + hAe1 + vAe0 + vAe1 + vAe2 + iAe0 + iAe1 + iAe2;
    const float Sp =       hAt0 + hAt1 + vAt0 + vAt1 + vAt2 + iAt0 + iAt1 + iAt2;
    const float Gq = 1.f + hBe0 + hBe1 + vBe0 + vBe1 + vBe2 + iBe0 + iBe1 + iBe2;
    const float Sq =       hBt0 + hBt1 + vBt0 + vBt1 + vBt2 + iBt0 + iBt1 + iBt2;

    // one rcp instead of two: ip = 1/Gp = rcp(Gp*Gq)*Gq, iq likewise
    const float P  = Gp * Gq;
    const float rP = frcp(P);
    const float ip = rP * Gq;
    const float iq = rP * Gp;
    const float hp = 0.5f * ip, hq = 0.5f * iq;

    float m = hp + hq;                       // center tap (g=1 for both)
    float mll = m * flog2(m);
#define MT(ea, eb) m = fmaf((ea), hp, (eb)*hq); mll = fmaf(m, flog2(m), mll);
    MT(hAe0, hBe0) MT(hAe1, hBe1)
    MT(vAe0, vBe0) MT(vAe1, vBe1) MT(vAe2, vBe2)
    MT(iAe0, iBe0) MT(iAe1, iBe1) MT(iAe2, iBe2)
#undef MT

    return fmaf(Sp, ip, Sq*iq) + flog2(P) + 2.f*mll;
}

__global__ __launch_bounds__(BLOCK, 4) void jsd_pixel_kernel(
    const float* __restrict__ A, const float* __restrict__ B,
    float* __restrict__ partial)
{
    const int bid   = blockIdx.x;
    const int ytile = bid >> 2;                      // 1024 row-pairs
    const int y0    = ytile << 1;                    // top pixel row (R1)
    const int x0    = ((bid & 3) << 9) + (threadIdx.x << 1);
    const int base  = y0 * W + x0;
    const bool hasL = (x0 > 0);
    const bool hasR = (x0 + 2 < W);

    // Rows: R0=y0-1 (mask), R1=y0, R2=y0+1, R3=y0+2 (mask). Cols C0..C3 = x0-1..x0+2.
    float a00,a01,a02,a03, a10,a11,a12,a13, a20,a21,a22,a23, a30,a31,a32,a33;
    float b00,b01,b02,b03, b10,b11,b12,b13, b20,b21,b22,b23, b30,b31,b32,b33;

#define LOAD_ROW(p0,p1,p2,p3, ptr, off) \
    { const float2 q_ = *(const float2*)((ptr)+(off)); p1=q_.x; p2=q_.y; \
      p0 = hasL ? (ptr)[(off)-1] : 0.f; p3 = hasR ? (ptr)[(off)+2] : 0.f; }

    LOAD_ROW(a10,a11,a12,a13, A, base)
    LOAD_ROW(a20,a21,a22,a23, A, base + W)
    LOAD_ROW(b10,b11,b12,b13, B, base)
    LOAD_ROW(b20,b21,b22,b23, B, base + W)
    if (y0 > 0) {                                     // block-uniform
        LOAD_ROW(a00,a01,a02,a03, A, base - W)
        LOAD_ROW(b00,b01,b02,b03, B, base - W)
    } else { a00=a01=a02=a03=0.f; b00=b01=b02=b03=0.f; }
    if (y0 + 2 < H) {
        LOAD_ROW(a30,a31,a32,a33, A, base + 2*W)
        LOAD_ROW(b30,b31,b32,b33, B, base + 2*W)
    } else { a30=a31=a32=a33=0.f; b30=b31=b32=b33=0.f; }
#undef LOAD_ROW

    // Precomputed pair exps: e = exp2(-t), w/t = e*t.
#define PAIR(e,t, u,v) float e,t; { float d_=(v)-(u); d_*=S_; const float q_=d_*d_; \
                                    e=fexp2(-q_); t=e*q_; }
    // horizontal pairs within rows R1, R2 (shared by adjacent pixels)
    PAIR(hA10,tA10, a10,a11) PAIR(hA11,tA11, a11,a12) PAIR(hA12,tA12, a12,a13)
    PAIR(hA20,tA20, a20,a21) PAIR(hA21,tA21, a21,a22) PAIR(hA22,tA22, a22,a23)
    PAIR(hB10,tB10, b10,b11) PAIR(hB11,tB11, b11,b12) PAIR(hB12,tB12, b12,b13)
    PAIR(hB20,tB20, b20,b21) PAIR(hB21,tB21, b21,b22) PAIR(hB22,tB22, b22,b23)
    // vertical/diagonal edges R1<->R2: vXY = edge (R1 col X, R2 col Y)
    PAIR(vA10,wA10, a11,a20) PAIR(vA11,wA11, a11,a21) PAIR(vA12,wA12, a11,a22)
    PAIR(vA21,wA21, a12,a21) PAIR(vA22,wA22, a12,a22) PAIR(vA23,wA23, a12,a23)
    PAIR(vA01,wA01, a10,a21) PAIR(vA32,wA32, a13,a22)
    PAIR(vB10,wB10, b11,b20) PAIR(vB11,wB11, b11,b21) PAIR(vB12,wB12, b11,b22)
    PAIR(vB21,wB21, b12,b21) PAIR(vB22,wB22, b12,b22) PAIR(vB23,wB23, b12,b23)
    PAIR(vB01,wB01, b10,b21) PAIR(vB32,wB32, b13,b22)
#undef PAIR

    float pacc;
    // (R1,C1): up = R0 cols 0..2; down edges v10,v11,v12
    pacc  = pixel_term(a00,a01,a02, a11, hA10,tA10, hA11,tA11,
                       vA10,wA10, vA11,wA11, vA12,wA12,
                       b00,b01,b02, b11, hB10,tB10, hB11,tB11,
                       vB10,wB10, vB11,wB11, vB12,wB12);
    // (R1,C2): up = R0 cols 1..3; down edges v21,v22,v23
    pacc += pixel_term(a01,a02,a03, a12, hA11,tA11, hA12,tA12,
                       vA21,wA21, vA22,wA22, vA23,wA23,
                       b01,b02,b03, b12, hB11,tB11, hB12,tB12,
                       vB21,wB21, vB22,wB22, vB23,wB23);
    // (R2,C1): down = R3 cols 0..2; up edges v01,v11,v21
    pacc += pixel_term(a30,a31,a32, a21, hA20,tA20, hA21,tA21,
                       vA01,wA01, vA11,wA11, vA21,wA21,
                       b30,b31,b32, b21, hB20,tB20, hB21,tB21,
                       vB01,wB01, vB11,wB11, vB21,wB21);
    // (R2,C2): down = R3 cols 1..3; up edges v12,v22,v32
    pacc += pixel_term(a31,a32,a33, a22, hA21,tA21, hA22,tA22,
                       vA12,wA12, vA22,wA22, vA32,wA32,
                       b31,b32,b33, b22, hB21,tB21, hB22,tB22,
                       vB12,wB12, vB22,wB22, vB32,wB32);

    // wave64 reduce, cross-wave via LDS
    #pragma unroll
    for (int off = 32; off > 0; off >>= 1)
        pacc += __shfl_down(pacc, off, 64);

    __shared__ float wsum[BLOCK / 64];
    const int lane = threadIdx.x & 63;
    const int wid  = threadIdx.x >> 6;
    if (lane == 0) wsum[wid] = pacc;
    __syncthreads();
    if (threadIdx.x == 0)
        partial[blockIdx.x] = wsum[0] + wsum[1] + wsum[2] + wsum[3];
}

// Deterministic final reduce of NBLOCKS partials (single block, 16 waves).
__global__ __launch_bounds__(RBLOCK) void jsd_final_reduce(
    const float* __restrict__ partial, float* __restrict__ out)
{
    float s = 0.f;
    #pragma unroll
    for (int i = 0; i < NBLOCKS / RBLOCK; ++i)
        s += partial[i * RBLOCK + threadIdx.x];

    #pragma unroll
    for (int off = 32; off > 0; off >>= 1)
        s += __shfl_down(s, off, 64);

    __shared__ float wsum[RBLOCK / 64];
    const int lane = threadIdx.x & 63;
    const int wid  = threadIdx.x >> 6;
    if (lane == 0) wsum[wid] = s;
    __syncthreads();
    if (threadIdx.x == 0) {
        float t = 0.f;
        #pragma unroll
        for (int i = 0; i < RBLOCK / 64; ++i) t += wsum[i];
        out[0] = -LN2_ * t;
    }
}

extern "C" void kernel_launch(void* const* d_in, const int* in_sizes, int n_in,
                              void* d_out, int out_size, void* d_ws, size_t ws_size,
                              hipStream_t stream) {
    const float* A = (const float*)d_in[0];
    const float* B = (const float*)d_in[1];
    float* out = (float*)d_out;
    float* partial = (float*)d_ws;    // NBLOCKS floats = 16 KiB

    jsd_pixel_kernel<<<NBLOCKS, BLOCK, 0, stream>>>(A, B, partial);
    jsd_final_reduce<<<1, RBLOCK, 0, stream>>>(partial, out);
}